// Round 1
// baseline (206.354 us; speedup 1.0000x reference)
//
#include <hip/hip_runtime.h>
#include <math.h>

#define NROWS 16384   // B*M
#define NN 32
#define NC 256
#define ND 128
#define RB 8          // rows per block
#define LNEPS 1e-5f
#define SCALE 0.08838834764831845f  // 1/sqrt(128)

// One-time transpose: WkT[d*NC + c] = Wk[c*ND + d]
__global__ void ca_transpose_wk(const float* __restrict__ Wk, float* __restrict__ WkT) {
    int i = blockIdx.x * 256 + threadIdx.x;  // i = d*NC + c
    int d = i >> 8;
    int c = i & (NC - 1);
    WkT[i] = Wk[c * ND + d];
}

template <bool USE_WKT>
__global__ __launch_bounds__(256)
void ca_fused_kernel(const float* __restrict__ x, const float* __restrict__ y,
                     const float* __restrict__ z,
                     const float* __restrict__ qg, const float* __restrict__ qb,
                     const float* __restrict__ Wq, const float* __restrict__ bq,
                     const float* __restrict__ kg, const float* __restrict__ kb,
                     const float* __restrict__ Wk, const float* __restrict__ bk,
                     const float* __restrict__ WkT, float* __restrict__ out) {
    // xh (normalized x rows) is reused as gp (= k_gamma * p) after phase 2.
    __shared__ __align__(16) float xh[RB * NC];
    __shared__ __align__(16) float qs[RB * ND];
    __shared__ float sc_const[RB];   // accumulates q.bk + sum_c(k_beta_c * p_c)
    float* gp = xh;

    const int tid = threadIdx.x;
    const int lane = tid & 63;
    const int wv = tid >> 6;          // wave 0..3
    const int row0 = blockIdx.x * RB;

    if (tid < RB) sc_const[tid] = 0.f;

    // ---- Phase 1: LayerNorm(x): wave wv handles rows 2wv, 2wv+1 ----
    {
        const float4 qg4 = *(const float4*)(qg + 4 * lane);
        const float4 qb4 = *(const float4*)(qb + 4 * lane);
        #pragma unroll
        for (int j = 0; j < 2; ++j) {
            const int r = 2 * wv + j;
            const float4 x4 = *(const float4*)(x + (size_t)(row0 + r) * NC + 4 * lane);
            float s1 = x4.x + x4.y + x4.z + x4.w;
            float s2 = x4.x * x4.x + x4.y * x4.y + x4.z * x4.z + x4.w * x4.w;
            #pragma unroll
            for (int m = 1; m < 64; m <<= 1) {
                s1 += __shfl_xor(s1, m, 64);
                s2 += __shfl_xor(s2, m, 64);
            }
            const float mu = s1 * (1.f / NC);
            const float var = s2 * (1.f / NC) - mu * mu;
            const float rstd = rsqrtf(var + LNEPS);
            float4 o;
            o.x = (x4.x - mu) * rstd * qg4.x + qb4.x;
            o.y = (x4.y - mu) * rstd * qg4.y + qb4.y;
            o.z = (x4.z - mu) * rstd * qg4.z + qb4.z;
            o.w = (x4.w - mu) * rstd * qg4.w + qb4.w;
            *(float4*)(xh + r * NC + 4 * lane) = o;
        }
    }
    __syncthreads();

    // ---- Phase 2: q[r][d] = sum_c xhat[r][c]*Wq[c][d] + bq[d]; q.bk partials ----
    {
        const int d = tid & (ND - 1);
        const int rg = tid >> 7;  // 0/1 -> rows rg*4 .. rg*4+3
        const float bqd = bq[d];
        float a0 = bqd, a1 = bqd, a2 = bqd, a3 = bqd;
        const float* xr = xh + rg * 4 * NC;
        #pragma unroll 4
        for (int c = 0; c < NC; ++c) {
            const float w = Wq[c * ND + d];   // coalesced; L2-resident
            a0 = fmaf(xr[0 * NC + c], w, a0); // LDS broadcast reads
            a1 = fmaf(xr[1 * NC + c], w, a1);
            a2 = fmaf(xr[2 * NC + c], w, a2);
            a3 = fmaf(xr[3 * NC + c], w, a3);
        }
        qs[(rg * 4 + 0) * ND + d] = a0;
        qs[(rg * 4 + 1) * ND + d] = a1;
        qs[(rg * 4 + 2) * ND + d] = a2;
        qs[(rg * 4 + 3) * ND + d] = a3;
        const float bkd = bk[d];
        float v0 = a0 * bkd, v1 = a1 * bkd, v2 = a2 * bkd, v3 = a3 * bkd;
        #pragma unroll
        for (int m = 1; m < 64; m <<= 1) {
            v0 += __shfl_xor(v0, m, 64);
            v1 += __shfl_xor(v1, m, 64);
            v2 += __shfl_xor(v2, m, 64);
            v3 += __shfl_xor(v3, m, 64);
        }
        if (lane == 0) {
            atomicAdd(&sc_const[rg * 4 + 0], v0);
            atomicAdd(&sc_const[rg * 4 + 1], v1);
            atomicAdd(&sc_const[rg * 4 + 2], v2);
            atomicAdd(&sc_const[rg * 4 + 3], v3);
        }
    }
    __syncthreads();

    // ---- Phase 3: p[r][c] = sum_d Wk[c][d]*q[r][d]; gp = kg*p; beta.p partials ----
    {
        const int c = tid;  // 0..255
        float acc[RB];
        #pragma unroll
        for (int r = 0; r < RB; ++r) acc[r] = 0.f;
        if constexpr (USE_WKT) {
            #pragma unroll 2
            for (int d = 0; d < ND; ++d) {
                const float w = WkT[d * NC + c];  // coalesced
                #pragma unroll
                for (int r = 0; r < RB; ++r) acc[r] = fmaf(qs[r * ND + d], w, acc[r]);
            }
        } else {
            const float* wr = Wk + c * ND;        // per-thread row; L1/L2-hit
            #pragma unroll 2
            for (int d = 0; d < ND; ++d) {
                const float w = wr[d];
                #pragma unroll
                for (int r = 0; r < RB; ++r) acc[r] = fmaf(qs[r * ND + d], w, acc[r]);
            }
        }
        const float kgc = kg[c];
        const float kbc = kb[c];
        float bpart[RB];
        #pragma unroll
        for (int r = 0; r < RB; ++r) {
            gp[r * NC + c] = kgc * acc[r];  // overwrites xh (safe: sync'd above)
            bpart[r] = kbc * acc[r];
        }
        #pragma unroll
        for (int m = 1; m < 64; m <<= 1) {
            #pragma unroll
            for (int r = 0; r < RB; ++r) bpart[r] += __shfl_xor(bpart[r], m, 64);
        }
        if (lane == 0) {
            #pragma unroll
            for (int r = 0; r < RB; ++r) atomicAdd(&sc_const[r], bpart[r]);
        }
    }
    __syncthreads();

    // ---- Phase 4: stream y; dots -> softmax -> weighted z sum ----
    #pragma unroll
    for (int j = 0; j < 2; ++j) {
        const int r = 2 * wv + j;
        const size_t grow = (size_t)(row0 + r);
        const float4 gp4 = *(const float4*)(gp + r * NC + 4 * lane);
        float sg = gp4.x + gp4.y + gp4.z + gp4.w;  // sum_c gamma_c * p_c
        #pragma unroll
        for (int m = 1; m < 64; m <<= 1) sg += __shfl_xor(sg, m, 64);
        const float cst = sc_const[r];
        const float* yrow = y + grow * (size_t)(NN * NC);
        float dv = 0.f;
        for (int n = 0; n < NN; ++n) {
            const float4 y4 = *(const float4*)(yrow + n * NC + 4 * lane);  // 1KB/wave coalesced
            float s1 = y4.x + y4.y + y4.z + y4.w;
            float s2 = y4.x * y4.x + y4.y * y4.y + y4.z * y4.z + y4.w * y4.w;
            float s3 = y4.x * gp4.x + y4.y * gp4.y + y4.z * gp4.z + y4.w * gp4.w;
            #pragma unroll
            for (int m = 1; m < 64; m <<= 1) {
                s1 += __shfl_xor(s1, m, 64);
                s2 += __shfl_xor(s2, m, 64);
                s3 += __shfl_xor(s3, m, 64);
            }
            const float mu = s1 * (1.f / NC);
            const float var = s2 * (1.f / NC) - mu * mu;
            const float rstd = rsqrtf(var + LNEPS);
            const float dotv = SCALE * (rstd * (s3 - mu * sg) + cst);
            dv = ((lane & 31) == n) ? dotv : dv;   // gather dots into lanes 0..31 (mirrored)
        }
        // softmax over 32 keys + weighted z sum, butterfly within 32-lane halves
        const float zv = z[grow * NN + (lane & 31)];
        float mx = dv;
        #pragma unroll
        for (int m = 1; m < 32; m <<= 1) mx = fmaxf(mx, __shfl_xor(mx, m, 64));
        const float e = __expf(dv - mx);
        float num = e * zv;
        float den = e;
        #pragma unroll
        for (int m = 1; m < 32; m <<= 1) {
            num += __shfl_xor(num, m, 64);
            den += __shfl_xor(den, m, 64);
        }
        if (lane == 0) out[grow] = num / den;
    }
}

extern "C" void kernel_launch(void* const* d_in, const int* in_sizes, int n_in,
                              void* d_out, int out_size, void* d_ws, size_t ws_size,
                              hipStream_t stream) {
    const float* x  = (const float*)d_in[0];
    const float* y  = (const float*)d_in[1];
    const float* z  = (const float*)d_in[2];
    const float* qg = (const float*)d_in[3];
    const float* qb = (const float*)d_in[4];
    const float* Wq = (const float*)d_in[5];
    const float* bq = (const float*)d_in[6];
    const float* kg = (const float*)d_in[7];
    const float* kb = (const float*)d_in[8];
    const float* Wk = (const float*)d_in[9];
    const float* bk = (const float*)d_in[10];
    float* out = (float*)d_out;

    const size_t wkt_bytes = (size_t)NC * ND * sizeof(float);
    if (ws_size >= wkt_bytes) {
        float* WkT = (float*)d_ws;
        ca_transpose_wk<<<(NC * ND) / 256, 256, 0, stream>>>(Wk, WkT);
        ca_fused_kernel<true><<<NROWS / RB, 256, 0, stream>>>(
            x, y, z, qg, qb, Wq, bq, kg, kb, Wk, bk, WkT, out);
    } else {
        ca_fused_kernel<false><<<NROWS / RB, 256, 0, stream>>>(
            x, y, z, qg, qb, Wq, bq, kg, kb, Wk, bk, nullptr, out);
    }
}